// Round 10
// baseline (223.397 us; speedup 1.0000x reference)
//
#include <hip/hip_runtime.h>
#include <hip/hip_bf16.h>
#include <type_traits>

// Conv2d B=32 IC=128 112x112 -> OC=256, K=3, s=2, p=1 (OH=OW=56).
// Round 10: r9 depth-3 fused pipeline, W-LDS round-trip removed:
//   - af fragments load DIRECTLY from wt2 (16B/lane coalesced; per-step 16KB
//     image is L1-resident; 576KB total L2-resident). Double-buffered named
//     afE/afO regs, prefetched one phase ahead, issued BEFORE X loads so
//     FIFO vmcnt waits for af don't drain the X pipeline.
//   - LDS = X only: 4 x 4KB buffers. Per-phase LDS traffic 52KB -> 20KB,
//     MFMA:ds_read 2:1 -> 4:1, occupancy 2 -> 3 blocks/CU.
//   - barrier/fence structure, slot discipline, verified mappings unchanged.

#define B_    32
#define IC_   128
#define H_    112
#define W_    112
#define HW_   (H_ * W_)
#define OC_   256
#define NPIX  (B_ * 56 * 56)              // 100352
#define NTILE (NPIX / 64)                 // 1568
#define WT2_BYTES ((size_t)36 * 16384)    // 589,824

typedef __attribute__((ext_vector_type(8))) short bf16x8;
typedef __attribute__((ext_vector_type(8))) float f32x8;
typedef __attribute__((ext_vector_type(4))) float f32x4;

struct AF { bf16x8 m[4]; };               // 4 A-fragments (literal-indexed)

static __device__ __forceinline__ unsigned f2bf_u(float f) {
  union { float f; unsigned u; } v; v.f = f;
  return (v.u + 0x7FFF + ((v.u >> 16) & 1)) >> 16;   // RNE; inputs finite
}

static __device__ __forceinline__ unsigned pk_bf16(float a, float b) {
  union { __hip_bfloat162 h; unsigned u; } c;
  c.h = __float22bfloat162_rn(float2{a, b});          // v_cvt_pk_bf16_f32
  return c.u;
}

// ---------------- k2: w -> wt2[step][q][oc][8] bf16 ----------------
__global__ __launch_bounds__(256) void wtrans2_kernel(
    const float* __restrict__ w, unsigned short* __restrict__ wt2) {
  const int t  = blockIdx.x * 256 + threadIdx.x;   // oc*128 + ic
  const int oc = t >> 7;
  const int ic = t & 127;
  const int icc = ic >> 5, q = (ic >> 3) & 3, e = ic & 7;
  const float* ws = w + (size_t)t * 9;             // w[oc][ic][*]
#pragma unroll
  for (int tap = 0; tap < 9; ++tap) {
    const int step = tap * 4 + icc;
    wt2[((size_t)(step * 4 + q) * 256 + oc) * 8 + e] =
        (unsigned short)f2bf_u(ws[tap]);
  }
}

// ---------------- k3: fused conv MFMA, depth-3 X pipeline, W direct --------
__global__ __launch_bounds__(256, 3) void conv_fused_kernel(
    const float* __restrict__ x, const unsigned short* __restrict__ wt2,
    const float* __restrict__ bias, float* __restrict__ out) {
  __shared__ unsigned short Xl[4][2048];  // [buf][q][64 pix][8ic] 4KB each

  const int tid = threadIdx.x, wav = tid >> 6, lane = tid & 63;

  // XCD-chunk swizzle: 1568 = 8*196, bijective.
  const int bid = blockIdx.x;
  const int pt  = (bid & 7) * (NTILE / 8) + (bid >> 3);
  const int p0  = pt * 64;
  const int b   = p0 / 3136;               // 64 | 3136: block never crosses b
  const int q0  = p0 - b * 3136;

  const int pixq = q0 + lane;
  const int oh = pixq / 56, ow = pixq - oh * 56;
  const int ih0 = 2 * oh - 1, iw0 = 2 * ow - 1;    // only -1 can be OOB
  const int boff = ih0 * W_ + iw0;
  const float* xpl = x + (size_t)b * IC_ * HW_;

  unsigned mtap = 0;                        // per-tap validity bitmask
#pragma unroll
  for (int kh = 0; kh < 3; ++kh)
#pragma unroll
    for (int kw = 0; kw < 3; ++kw)
      if (ih0 + kh >= 0 && iw0 + kw >= 0) mtap |= 1u << (kh * 3 + kw);

  const int l15 = lane & 15, lg = lane >> 4;

  auto loadX = [&](int s) -> f32x8 {        // 8 coalesced f32 loads -> regs
    const int tap = s >> 2, icc = s & 3;
    const int kh = tap / 3, kw = tap - kh * 3;
    const bool m = (mtap >> tap) & 1;
    const int o  = boff + kh * W_ + kw + (icc * 32 + wav * 8) * HW_;
    const int ob = m ? o : (icc * 32 + wav * 8) * HW_;   // safe in-bounds addr
    f32x8 v;
#pragma unroll
    for (int k = 0; k < 8; ++k) {
      const float t = xpl[ob + k * HW_];
      v[k] = m ? t : 0.f;
    }
    return v;
  };
  auto loadAF = [&](int s) -> AF {          // 4x 16B coalesced, L1-resident
    const unsigned short* src =
        wt2 + (size_t)s * 8192 + lg * 2048 + (wav * 64 + l15) * 8;
    AF r;
#pragma unroll
    for (int mi = 0; mi < 4; ++mi)
      r.m[mi] = *reinterpret_cast<const bf16x8*>(src + mi * 128);
    return r;
  };
  auto writeX = [&](const f32x8& v, int buf) {   // pack + one 16B LDS write
    uint4 p;
    p.x = pk_bf16(v[0], v[1]);
    p.y = pk_bf16(v[2], v[3]);
    p.z = pk_bf16(v[4], v[5]);
    p.w = pk_bf16(v[6], v[7]);
    *reinterpret_cast<uint4*>(
        reinterpret_cast<char*>(&Xl[buf][0]) + wav * 1024 + lane * 16) = p;
  };

  f32x4 acc[4][4] = {};

  auto compute = [&](int buf, const AF& af) {
    bf16x8 bx[4];
    const unsigned short* xb2 = &Xl[buf][0] + lg * 512;   // q stride 1KB
#pragma unroll
    for (int ni = 0; ni < 4; ++ni)
      bx[ni] = *reinterpret_cast<const bf16x8*>(xb2 + (ni * 16 + l15) * 8);
#pragma unroll
    for (int mi = 0; mi < 4; ++mi)
#pragma unroll
      for (int ni = 0; ni < 4; ++ni)
        acc[mi][ni] = __builtin_amdgcn_mfma_f32_16x16x32_bf16(
            af.m[mi], bx[ni], acc[mi][ni], 0, 0, 0);
  };

  // Three named X register slots; step t lives in slot t%3, LDS buf t&3.
  f32x8 xa, xb_, xc;
  AF afE, afO;

  // Prologue: af for step 0 FIRST (so nothing forces its wait to drain X),
  // then X issues for steps 0..2, LDS-commit step 0 into buf 0.
  afE = loadAF(0);
  xa = loadX(0);
  xb_ = loadX(1);
  xc = loadX(2);
  writeX(xa, 0);
  asm volatile("s_waitcnt lgkmcnt(0)" ::: "memory");
  __builtin_amdgcn_sched_barrier(0);
  __builtin_amdgcn_s_barrier();
  __builtin_amdgcn_sched_barrier(0);

  // Phase K (s = sb+K): prefetch af(s+1) into afNxt (issued before X so the
  // FIFO vmcnt wait at next phase's MFMAs doesn't drain the X queue), issue
  // X(s+3) into slot K%3, LDS-commit X(s+1) from slot (K+1)%3 into buf
  // (K+1)&3, fence+barrier, MFMA step s from buf K&3 with afCur.
  auto phase = [&](auto KC, int sb, AF& afCur, AF& afNxt) {
    constexpr int K = decltype(KC)::value;
    const int s = sb + K;
    if (s + 1 < 36) afNxt = loadAF(s + 1);
    f32x8& xn = (K % 3 == 0) ? xa : (K % 3 == 1) ? xb_ : xc;
    f32x8& xm = ((K + 1) % 3 == 0) ? xa : ((K + 1) % 3 == 1) ? xb_ : xc;
    if (s + 3 < 36) xn = loadX(s + 3);
    if (s + 1 < 36) writeX(xm, (K + 1) & 3);
    asm volatile("s_waitcnt lgkmcnt(0)" ::: "memory");
    __builtin_amdgcn_sched_barrier(0);
    __builtin_amdgcn_s_barrier();
    __builtin_amdgcn_sched_barrier(0);
    compute(K & 3, afCur);
  };

#define PHE(K) phase(std::integral_constant<int, K>{}, sb, afE, afO)
#define PHO(K) phase(std::integral_constant<int, K>{}, sb, afO, afE)
  for (int sb = 0; sb < 36; sb += 12) {    // 12 = lcm(3 slots, 4 bufs), even
    PHE(0); PHO(1); PHE(2); PHO(3); PHE(4); PHO(5);
    PHE(6); PHO(7); PHE(8); PHO(9); PHE(10); PHO(11);
  }
#undef PHE
#undef PHO

  // Epilogue: lanes sweep pixels -> coalesced stores.
#pragma unroll
  for (int mi = 0; mi < 4; ++mi) {
#pragma unroll
    for (int j = 0; j < 4; ++j) {
      const int oc = wav * 64 + mi * 16 + lg * 4 + j;
      const float bv = bias[oc];
#pragma unroll
      for (int ni = 0; ni < 4; ++ni) {
        const int qp = q0 + ni * 16 + l15;
        out[((size_t)b * OC_ + oc) * 3136 + qp] = acc[mi][ni][j] + bv;
      }
    }
  }
}

// ---------------- fallback: fp32 direct conv ----------------
__global__ __launch_bounds__(256) void conv2d_f32_kernel(
    const float* __restrict__ x, const float* __restrict__ w,
    const float* __restrict__ bias, float* __restrict__ out) {
  __shared__ float wlds[IC_ * 9][8];
  const int b   = blockIdx.z;
  const int oc0 = blockIdx.y * 8;
  const float* wsrc = w + (size_t)oc0 * (IC_ * 9);
  for (int i = threadIdx.x; i < IC_ * 9 * 8; i += 256) {
    const int j = i / (IC_ * 9);
    const int t = i - j * (IC_ * 9);
    wlds[t][j] = wsrc[(size_t)j * (IC_ * 9) + t];
  }
  __syncthreads();
  const int p  = blockIdx.x * 256 + threadIdx.x;
  const int ow = p % 56;
  const int oh = p / 56;
  const bool pv = (oh < 56);
  const int ih0 = 2 * oh - 1;
  const int iw0 = 2 * ow - 1;
  const float* xb = x + (size_t)b * IC_ * HW_ + (ptrdiff_t)ih0 * W_ + iw0;
  float acc[8];
#pragma unroll
  for (int j = 0; j < 8; ++j) acc[j] = 0.f;
  for (int ic = 0; ic < IC_; ++ic) {
    const float* xc = xb + (size_t)ic * HW_;
#pragma unroll
    for (int kh = 0; kh < 3; ++kh) {
      const bool hv = pv && ((ih0 + kh) >= 0);
#pragma unroll
      for (int kw = 0; kw < 3; ++kw) {
        const bool v = hv && ((iw0 + kw) >= 0);
        const float xv = v ? xc[kh * W_ + kw] : 0.f;
        const int t = ic * 9 + kh * 3 + kw;
        const float4 w0 = *reinterpret_cast<const float4*>(&wlds[t][0]);
        const float4 w1 = *reinterpret_cast<const float4*>(&wlds[t][4]);
        acc[0] = fmaf(xv, w0.x, acc[0]); acc[1] = fmaf(xv, w0.y, acc[1]);
        acc[2] = fmaf(xv, w0.z, acc[2]); acc[3] = fmaf(xv, w0.w, acc[3]);
        acc[4] = fmaf(xv, w1.x, acc[4]); acc[5] = fmaf(xv, w1.y, acc[5]);
        acc[6] = fmaf(xv, w1.z, acc[6]); acc[7] = fmaf(xv, w1.w, acc[7]);
      }
    }
  }
  if (pv) {
#pragma unroll
    for (int j = 0; j < 8; ++j)
      out[(((size_t)(b * OC_ + oc0 + j)) * 56 + oh) * 56 + ow] =
          acc[j] + bias[oc0 + j];
  }
}

extern "C" void kernel_launch(void* const* d_in, const int* in_sizes, int n_in,
                              void* d_out, int out_size, void* d_ws, size_t ws_size,
                              hipStream_t stream) {
  const float* x    = (const float*)d_in[0];
  const float* w    = (const float*)d_in[1];
  const float* bias = (const float*)d_in[2];
  float* out        = (float*)d_out;

  if (ws_size >= WT2_BYTES) {
    unsigned short* wt2 = (unsigned short*)d_ws;
    wtrans2_kernel<<<128, 256, 0, stream>>>(w, wt2);
    conv_fused_kernel<<<NTILE, 256, 0, stream>>>(x, wt2, bias, out);
  } else {
    conv2d_f32_kernel<<<dim3(13, OC_ / 8, B_), 256, 0, stream>>>(x, w, bias, out);
  }
}

// Round 11
// 175.287 us; speedup vs baseline: 1.2745x; 1.2745x over previous
//
#include <hip/hip_runtime.h>
#include <hip/hip_bf16.h>

// Conv2d B=32 IC=128 112x112 -> OC=256, K=3, s=2, p=1 (OH=OW=56).
// Round 11: back to the measured-best SPLIT pipeline (r6, 157us), GEMM fixed
// per its counters (MfmaUtil 20.7%, 7.2M bank conflicts, barrier-drain):
//   - counted-vmcnt raw-barrier pipeline (T3/T4): 4 LDS bufs, iter s issues
//     stage(s+2), s_waitcnt vmcnt(8) (8 loads stay in flight across the
//     barrier), sched_barrier(0)-fenced s_barrier, compute(s&3).
//   - granule-major LDS [q][row][8ic] for W and X (r7-proven 0-conflict);
//     W staged linearly from wt2 images, X with per-lane pixel addressing.
//   k1 xtrans: byte-identical r3 (measured). k2: r7 wtrans2.

#define B_    32
#define IC_   128
#define H_    112
#define W_    112
#define HW_   (H_ * W_)
#define OC_   256
#define HP    113
#define NPIX  (B_ * 56 * 56)              // 100352
#define XT_BYTES ((size_t)B_ * HP * HP * IC_ * 2)   // 104,603,648
#define WT2_BYTES ((size_t)36 * 16384)    // 589,824

typedef __attribute__((ext_vector_type(8))) short bf16x8;
typedef __attribute__((ext_vector_type(4))) float f32x4;

static __device__ __forceinline__ unsigned f2bf_u(float f) {
  union { float f; unsigned u; } v; v.f = f;
  return (v.u + 0x7FFF + ((v.u >> 16) & 1)) >> 16;   // RNE; inputs finite
}

// ---------------- k1: x -> padded channels-last bf16 (r3, measured) --------
__global__ __launch_bounds__(256) void xtrans_kernel(
    const float* __restrict__ x, unsigned short* __restrict__ xt) {
  __shared__ unsigned short lds[128 * 128];   // 32 KiB, row stride 128 ush
  const int ihp = blockIdx.x;                 // 0..112 (0 = zero pad row)
  const int b   = blockIdx.y;
  const int tid = threadIdx.x;

  if (ihp > 0) {
    const float* xp = x + (size_t)b * IC_ * HW_ + (size_t)(ihp - 1) * W_;
#pragma unroll
    for (int it = 0; it < 16; ++it) {
      const int i  = tid + it * 256;          // (ic, g) over 128 x 32
      const int ic = i >> 5;
      const int g  = i & 31;                  // 16B granule along iw
      if (g < 28) {
        const float4 v = *reinterpret_cast<const float4*>(
            xp + (size_t)ic * HW_ + g * 4);
        uint2 p;
        p.x = f2bf_u(v.x) | (f2bf_u(v.y) << 16);
        p.y = f2bf_u(v.z) | (f2bf_u(v.w) << 16);
        const int gs = g ^ (((ic >> 3) & 7) << 2);
        *reinterpret_cast<uint2*>(&lds[ic * 128 + gs * 4]) = p;
      }
    }
  }
  __syncthreads();

  unsigned short* xrow = xt + ((size_t)(b * HP + ihp)) * (HP * IC_);
  const bool live = (ihp > 0);
#pragma unroll
  for (int it = 0; it < 8; ++it) {
    const int e = tid + it * 256;             // (iwp, icg) over 113 x 16
    if (e >= HP * 16) break;
    const int iwp = e >> 4;
    const int icg = e & 15;
    uint4 v = {0u, 0u, 0u, 0u};
    if (live && iwp > 0) {
      const int iw  = iwp - 1;
      const int col = ((iw >> 2) ^ ((icg & 7) << 2)) * 4 + (iw & 3);
      const int r0  = icg * 8;
      unsigned u0 = lds[(r0 + 0) * 128 + col];
      unsigned u1 = lds[(r0 + 1) * 128 + col];
      unsigned u2 = lds[(r0 + 2) * 128 + col];
      unsigned u3 = lds[(r0 + 3) * 128 + col];
      unsigned u4 = lds[(r0 + 4) * 128 + col];
      unsigned u5 = lds[(r0 + 5) * 128 + col];
      unsigned u6 = lds[(r0 + 6) * 128 + col];
      unsigned u7 = lds[(r0 + 7) * 128 + col];
      v.x = u0 | (u1 << 16);
      v.y = u2 | (u3 << 16);
      v.z = u4 | (u5 << 16);
      v.w = u6 | (u7 << 16);
    }
    *reinterpret_cast<uint4*>(xrow + iwp * IC_ + icg * 8) = v;
  }
}

// ---------------- k2: w -> wt2[step][q][oc 0..255][8ic] bf16 ----------------
__global__ __launch_bounds__(256) void wtrans2_kernel(
    const float* __restrict__ w, unsigned short* __restrict__ wt2) {
  const int t  = blockIdx.x * 256 + threadIdx.x;   // oc*128 + ic
  const int oc = t >> 7;
  const int ic = t & 127;
  const int icc = ic >> 5, q = (ic >> 3) & 3, e = ic & 7;
  const float* ws = w + (size_t)t * 9;             // w[oc][ic][*]
#pragma unroll
  for (int tap = 0; tap < 9; ++tap) {
    const int step = tap * 4 + icc;
    wt2[((size_t)(step * 4 + q) * 256 + oc) * 8 + e] =
        (unsigned short)f2bf_u(ws[tap]);
  }
}

// ---------------- k3: MFMA GEMM, counted-vmcnt 4-buf pipeline ----------------
__global__ __launch_bounds__(256, 2) void conv_mfma_kernel(
    const unsigned short* __restrict__ xt, const unsigned short* __restrict__ wt2,
    const float* __restrict__ bias, float* __restrict__ out) {
  __shared__ unsigned short Wl[4][4096];  // [buf][q][128 oc][8ic]  8KB each
  __shared__ unsigned short Xl[4][4096];  // [buf][q][128 pix][8ic] 8KB each

  const int tid = threadIdx.x, wav = tid >> 6, lane = tid & 63;

  // XCD-chunk swizzle over 1568 blocks: chunk 196, bijective (r6-verified).
  const int bid  = blockIdx.x;
  const int wgid = (bid & 7) * 196 + (bid >> 3);
  const int mt  = wgid & 1;            // oc half (fast: pairs share X in L2)
  const int pt  = wgid >> 1;           // pixel tile
  const int oc0 = mt * 128;
  const int p0  = pt * 128;

  // --- staging addresses. Wave stages the q=wav plane of each tile. ---
  // X: shot i covers pixels p0 + i*64 + lane (per-lane global addr).
  const char* xsrc[2];
#pragma unroll
  for (int i = 0; i < 2; ++i) {
    const int pix = p0 + i * 64 + lane;
    const int b   = pix / 3136;
    const int q   = pix - b * 3136;
    const int oh  = q / 56;
    const int ow  = q - oh * 56;
    const size_t e = (((size_t)b * HP + 2 * oh) * HP + 2 * ow) * IC_;
    xsrc[i] = reinterpret_cast<const char*>(xt) + e * 2 + wav * 16;
  }
  // W: wt2[step] image is [q][256 oc][16B]; q plane 4KB, mt half 2KB.
  const char* wbase = reinterpret_cast<const char*>(wt2)
                    + wav * 4096 + mt * 2048 + lane * 16;

  auto stage = [&](int s, int buf) {
    const int tap = s >> 2, icc = s & 3;
    const int kh = tap / 3, kw = tap - kh * 3;
    const size_t xoff = ((size_t)(kh * HP + kw) * IC_ + icc * 32) * 2;
    const char* wsrc = wbase + (size_t)s * 16384;
    char* xd = reinterpret_cast<char*>(&Xl[buf][0]) + wav * 2048;
    char* wd = reinterpret_cast<char*>(&Wl[buf][0]) + wav * 2048;
#pragma unroll
    for (int i = 0; i < 2; ++i) {     // dest gets +lane*16 in hardware
      __builtin_amdgcn_global_load_lds(
          (const __attribute__((address_space(1))) void*)(xsrc[i] + xoff),
          (__attribute__((address_space(3))) void*)(xd + i * 1024), 16, 0, 0);
      __builtin_amdgcn_global_load_lds(
          (const __attribute__((address_space(1))) void*)(wsrc + i * 1024),
          (__attribute__((address_space(3))) void*)(wd + i * 1024), 16, 0, 0);
    }
  };

  const int wm = wav >> 1, wn = wav & 1;
  const int l15 = lane & 15, lg = lane >> 4;

  f32x4 acc[4][4] = {};

  auto compute = [&](int buf) {
    bf16x8 af[4], bx[4];
    const unsigned short* wb  = &Wl[buf][0] + lg * 1024;  // q stride 2KB
    const unsigned short* xb2 = &Xl[buf][0] + lg * 1024;
#pragma unroll
    for (int mi = 0; mi < 4; ++mi)
      af[mi] = *reinterpret_cast<const bf16x8*>(
          wb + (wm * 64 + mi * 16 + l15) * 8);
#pragma unroll
    for (int ni = 0; ni < 4; ++ni)
      bx[ni] = *reinterpret_cast<const bf16x8*>(
          xb2 + (wn * 64 + ni * 16 + l15) * 8);
#pragma unroll
    for (int mi = 0; mi < 4; ++mi)
#pragma unroll
      for (int ni = 0; ni < 4; ++ni)
        acc[mi][ni] = __builtin_amdgcn_mfma_f32_16x16x32_bf16(
            af[mi], bx[ni], acc[mi][ni], 0, 0, 0);
  };

#define FENCED_BARRIER()                          \
  __builtin_amdgcn_sched_barrier(0);              \
  __builtin_amdgcn_s_barrier();                   \
  __builtin_amdgcn_sched_barrier(0)

  // Prologue: stages 0,1 in flight; wait only stage(0) (vmcnt<=4).
  stage(0, 0);
  stage(1, 1);
  asm volatile("s_waitcnt vmcnt(4)" ::: "memory");
  FENCED_BARRIER();

  // Steady state: issue stage(s+2), wait vmcnt(8) (=> stage(s) retired;
  // s+1,s+2 stay in flight across the barrier), barrier, compute(s).
  for (int s = 0; s < 34; ++s) {
    stage(s + 2, (s + 2) & 3);
    asm volatile("s_waitcnt vmcnt(8)" ::: "memory");
    FENCED_BARRIER();
    compute(s & 3);
  }
  // Tail: s=34 (stage 35 outstanding), s=35.
  asm volatile("s_waitcnt vmcnt(4)" ::: "memory");
  FENCED_BARRIER();
  compute(34 & 3);
  asm volatile("s_waitcnt vmcnt(0)" ::: "memory");
  FENCED_BARRIER();
  compute(35 & 3);
#undef FENCED_BARRIER

  // Epilogue: lanes sweep pixels -> coalesced stores (per-pixel batch).
#pragma unroll
  for (int mi = 0; mi < 4; ++mi) {
#pragma unroll
    for (int j = 0; j < 4; ++j) {
      const int oc = oc0 + wm * 64 + mi * 16 + lg * 4 + j;
      const float bv = bias[oc];
#pragma unroll
      for (int ni = 0; ni < 4; ++ni) {
        const int pix = p0 + wn * 64 + ni * 16 + l15;
        const int b   = pix / 3136;
        const int q   = pix - b * 3136;
        out[((size_t)b * OC_ + oc) * 3136 + q] = acc[mi][ni][j] + bv;
      }
    }
  }
}

// ---------------- fallback: fp32 direct conv ----------------
__global__ __launch_bounds__(256) void conv2d_f32_kernel(
    const float* __restrict__ x, const float* __restrict__ w,
    const float* __restrict__ bias, float* __restrict__ out) {
  __shared__ float wlds[IC_ * 9][8];
  const int b   = blockIdx.z;
  const int oc0 = blockIdx.y * 8;
  const float* wsrc = w + (size_t)oc0 * (IC_ * 9);
  for (int i = threadIdx.x; i < IC_ * 9 * 8; i += 256) {
    const int j = i / (IC_ * 9);
    const int t = i - j * (IC_ * 9);
    wlds[t][j] = wsrc[(size_t)j * (IC_ * 9) + t];
  }
  __syncthreads();
  const int p  = blockIdx.x * 256 + threadIdx.x;
  const int ow = p % 56;
  const int oh = p / 56;
  const bool pv = (oh < 56);
  const int ih0 = 2 * oh - 1;
  const int iw0 = 2 * ow - 1;
  const float* xb = x + (size_t)b * IC_ * HW_ + (ptrdiff_t)ih0 * W_ + iw0;
  float acc[8];
#pragma unroll
  for (int j = 0; j < 8; ++j) acc[j] = 0.f;
  for (int ic = 0; ic < IC_; ++ic) {
    const float* xc = xb + (size_t)ic * HW_;
#pragma unroll
    for (int kh = 0; kh < 3; ++kh) {
      const bool hv = pv && ((ih0 + kh) >= 0);
#pragma unroll
      for (int kw = 0; kw < 3; ++kw) {
        const bool v = hv && ((iw0 + kw) >= 0);
        const float xv = v ? xc[kh * W_ + kw] : 0.f;
        const int t = ic * 9 + kh * 3 + kw;
        const float4 w0 = *reinterpret_cast<const float4*>(&wlds[t][0]);
        const float4 w1 = *reinterpret_cast<const float4*>(&wlds[t][4]);
        acc[0] = fmaf(xv, w0.x, acc[0]); acc[1] = fmaf(xv, w0.y, acc[1]);
        acc[2] = fmaf(xv, w0.z, acc[2]); acc[3] = fmaf(xv, w0.w, acc[3]);
        acc[4] = fmaf(xv, w1.x, acc[4]); acc[5] = fmaf(xv, w1.y, acc[5]);
        acc[6] = fmaf(xv, w1.z, acc[6]); acc[7] = fmaf(xv, w1.w, acc[7]);
      }
    }
  }
  if (pv) {
#pragma unroll
    for (int j = 0; j < 8; ++j)
      out[(((size_t)(b * OC_ + oc0 + j)) * 56 + oh) * 56 + ow] =
          acc[j] + bias[oc0 + j];
  }
}

extern "C" void kernel_launch(void* const* d_in, const int* in_sizes, int n_in,
                              void* d_out, int out_size, void* d_ws, size_t ws_size,
                              hipStream_t stream) {
  const float* x    = (const float*)d_in[0];
  const float* w    = (const float*)d_in[1];
  const float* bias = (const float*)d_in[2];
  float* out        = (float*)d_out;

  if (ws_size >= XT_BYTES + WT2_BYTES) {
    unsigned short* xt  = (unsigned short*)d_ws;
    unsigned short* wt2 = (unsigned short*)((char*)d_ws + XT_BYTES);
    xtrans_kernel<<<dim3(HP, B_), 256, 0, stream>>>(x, xt);
    wtrans2_kernel<<<128, 256, 0, stream>>>(w, wt2);
    conv_mfma_kernel<<<NPIX / 64, 256, 0, stream>>>(xt, wt2, bias, out);
  } else {
    conv2d_f32_kernel<<<dim3(13, OC_ / 8, B_), 256, 0, stream>>>(x, w, bias, out);
  }
}